// Round 1
// baseline (172.049 us; speedup 1.0000x reference)
//
#include <hip/hip_runtime.h>

// Chamfer distance: B=8, N=M=8192, D=3, fp32.
// d(n,m) = |p_n|^2 + |g_m|^2 - 2 p_n.g_m ; min over opposite set per point;
// out = mean_b( 0.5*mean_n(min) + 0.5*mean_m(min) ) * 100
//
// Strategy: pure VALU problem (no fp32 MFMA on CDNA4). Inner pair = 5 VALU
// instr via norm expansion. Dst points staged in LDS as float4(x,y,z,norm);
// inner-loop reads are wave-uniform -> LDS broadcast (conflict-free).
// P=2 src points/thread amortizes the ds_read_b128. M split in 2 for
// 512 blocks (2 blocks/CU). Partial mins -> ws, second kernel reduces.

#define B_DIM 8
#define N_DIM 8192
#define TILE  2048
#define SPLIT 2
#define PPT   2
#define BLOCK 256

__global__ __launch_bounds__(BLOCK, 2) void chamfer_partial(
    const float* __restrict__ pred, const float* __restrict__ gt,
    float* __restrict__ ws)
{
    __shared__ float4 tile[TILE];   // 32 KB
    const int tid   = threadIdx.x;
    const int z     = blockIdx.z;        // 0..15 : b + dir*8
    const int b     = z & (B_DIM - 1);
    const int dir   = z >> 3;            // 0: pred->gt, 1: gt->pred
    const int s     = blockIdx.y;        // M-split
    const int chunk = blockIdx.x;        // N-chunk

    const float* src = dir ? gt   : pred;
    const float* dst = dir ? pred : gt;
    const float* srcb = src + (size_t)b * N_DIM * 3;
    const float* dstb = dst + (size_t)b * N_DIM * 3;

    const int n0 = chunk * (BLOCK * PPT) + tid;
    const int n1 = n0 + BLOCK;
    const float x0 = srcb[n0*3+0], y0 = srcb[n0*3+1], z0 = srcb[n0*3+2];
    const float x1 = srcb[n1*3+0], y1 = srcb[n1*3+1], z1 = srcb[n1*3+2];
    const float pn0 = x0*x0 + y0*y0 + z0*z0;
    const float pn1 = x1*x1 + y1*y1 + z1*z1;

    float best0 = 1e30f, best1 = 1e30f;

    const int m_begin = s * (N_DIM / SPLIT);
    const int n_tiles = (N_DIM / SPLIT) / TILE;
    for (int t = 0; t < n_tiles; ++t) {
        const int base = m_begin + t * TILE;
        __syncthreads();                 // protect prior tile reads
        #pragma unroll
        for (int k = 0; k < TILE / BLOCK; ++k) {
            const int idx = k * BLOCK + tid;
            const int m = base + idx;
            const float gx = dstb[m*3+0], gy = dstb[m*3+1], gz = dstb[m*3+2];
            const float gn = gx*gx + gy*gy + gz*gz;
            tile[idx] = make_float4(gx, gy, gz, gn);
        }
        __syncthreads();
        #pragma unroll 8
        for (int j = 0; j < TILE; ++j) {
            const float4 g = tile[j];    // wave-uniform -> broadcast
            const float dot0 = fmaf(x0, g.x, fmaf(y0, g.y, z0 * g.z));
            const float dot1 = fmaf(x1, g.x, fmaf(y1, g.y, z1 * g.z));
            best0 = fminf(best0, fmaf(-2.0f, dot0, g.w));
            best1 = fminf(best1, fmaf(-2.0f, dot1, g.w));
        }
    }
    // ws layout: [dir][b][split][N]
    const size_t wbase = (((size_t)dir * B_DIM + b) * SPLIT + s) * N_DIM;
    ws[wbase + n0] = best0 + pn0;
    ws[wbase + n1] = best1 + pn1;
}

__global__ __launch_bounds__(256) void chamfer_reduce(
    const float* __restrict__ ws, float* __restrict__ out)
{
    const float scale = 100.0f * 0.5f / ((float)B_DIM * (float)N_DIM);
    const int i  = blockIdx.x * 256 + threadIdx.x;   // over 2*B*N
    const int db = i / N_DIM;
    const int n  = i - db * N_DIM;
    float v = 1e30f;
    #pragma unroll
    for (int s = 0; s < SPLIT; ++s)
        v = fminf(v, ws[((size_t)db * SPLIT + s) * N_DIM + n]);
    // wave64 reduce
    for (int off = 32; off > 0; off >>= 1)
        v += __shfl_down(v, off, 64);
    __shared__ float wsum[4];
    const int lane = threadIdx.x & 63, w = threadIdx.x >> 6;
    if (lane == 0) wsum[w] = v;
    __syncthreads();
    if (threadIdx.x == 0) {
        const float t = wsum[0] + wsum[1] + wsum[2] + wsum[3];
        atomicAdd(out, t * scale);
    }
}

extern "C" void kernel_launch(void* const* d_in, const int* in_sizes, int n_in,
                              void* d_out, int out_size, void* d_ws, size_t ws_size,
                              hipStream_t stream) {
    const float* pred = (const float*)d_in[0];
    const float* gt   = (const float*)d_in[1];
    float* out = (float*)d_out;
    float* ws  = (float*)d_ws;     // needs 2*B*SPLIT*N*4 = 1 MiB

    hipMemsetAsync(out, 0, sizeof(float), stream);

    dim3 grid(N_DIM / (BLOCK * PPT), SPLIT, 2 * B_DIM);   // 16 x 2 x 16 = 512 blocks
    chamfer_partial<<<grid, BLOCK, 0, stream>>>(pred, gt, ws);

    chamfer_reduce<<<(2 * B_DIM * N_DIM) / 256, 256, 0, stream>>>(ws, out);
}

// Round 2
// 146.812 us; speedup vs baseline: 1.1719x; 1.1719x over previous
//
#include <hip/hip_runtime.h>

// Chamfer distance: B=8, N=M=8192, D=3, fp32.
// R2: (a) tile stores (-2gx,-2gy,-2gz,|g|^2) -> dist = 3 FMA + 1 MIN = 4 VALU/pair
//     (b) PPT=4, SPLIT=8 -> 1024 blocks = 4 blocks/CU = 4 waves/SIMD (R1 had 2,
//         exposing ds_read latency; Occupancy was 21%).
// VALU floor: 1.074G pairs * 4 instr / 64 lanes / 1024 SIMDs * 2cyc @2.4GHz = 55us.

#define B_DIM 8
#define N_DIM 8192
#define TILE  1024
#define SPLIT 8
#define PPT   4
#define BLOCK 256

__global__ __launch_bounds__(BLOCK, 4) void chamfer_partial(
    const float* __restrict__ pred, const float* __restrict__ gt,
    float* __restrict__ ws)
{
    __shared__ float4 tile[TILE];   // 16 KB
    const int tid   = threadIdx.x;
    const int z     = blockIdx.z;        // 0..15 : b + dir*8
    const int b     = z & (B_DIM - 1);
    const int dir   = z >> 3;            // 0: pred->gt, 1: gt->pred
    const int s     = blockIdx.y;        // M-split
    const int chunk = blockIdx.x;        // N-chunk

    const float* src  = dir ? gt   : pred;
    const float* dst  = dir ? pred : gt;
    const float* srcb = src + (size_t)b * N_DIM * 3;
    const float* dstb = dst + (size_t)b * N_DIM * 3;

    // 4 source points per thread, stride BLOCK apart
    float px[PPT], py[PPT], pz[PPT], pn[PPT], best[PPT];
    const int nbase = chunk * (BLOCK * PPT) + tid;
    #pragma unroll
    for (int p = 0; p < PPT; ++p) {
        const int n = nbase + p * BLOCK;
        px[p] = srcb[n*3+0]; py[p] = srcb[n*3+1]; pz[p] = srcb[n*3+2];
        pn[p] = px[p]*px[p] + py[p]*py[p] + pz[p]*pz[p];
        best[p] = 1e30f;
    }

    const int m_begin = s * (N_DIM / SPLIT);
    const int n_tiles = (N_DIM / SPLIT) / TILE;
    for (int t = 0; t < n_tiles; ++t) {
        const int base = m_begin + t * TILE;
        __syncthreads();
        #pragma unroll
        for (int k = 0; k < TILE / BLOCK; ++k) {
            const int idx = k * BLOCK + tid;
            const int m = base + idx;
            const float gx = dstb[m*3+0], gy = dstb[m*3+1], gz = dstb[m*3+2];
            const float gn = gx*gx + gy*gy + gz*gz;
            tile[idx] = make_float4(-2.0f*gx, -2.0f*gy, -2.0f*gz, gn);
        }
        __syncthreads();
        #pragma unroll 4
        for (int j = 0; j < TILE; ++j) {
            const float4 g = tile[j];    // wave-uniform -> LDS broadcast
            #pragma unroll
            for (int p = 0; p < PPT; ++p) {
                const float d = fmaf(g.x, px[p], fmaf(g.y, py[p],
                                 fmaf(g.z, pz[p], g.w)));
                best[p] = fminf(best[p], d);
            }
        }
    }
    // ws layout: [dir][b][split][N]
    const size_t wbase = (((size_t)dir * B_DIM + b) * SPLIT + s) * N_DIM;
    #pragma unroll
    for (int p = 0; p < PPT; ++p)
        ws[wbase + nbase + p * BLOCK] = best[p] + pn[p];
}

__global__ __launch_bounds__(256) void chamfer_reduce(
    const float* __restrict__ ws, float* __restrict__ out)
{
    const float scale = 100.0f * 0.5f / ((float)B_DIM * (float)N_DIM);
    const int i  = blockIdx.x * 256 + threadIdx.x;   // over 2*B*N
    const int db = i / N_DIM;
    const int n  = i - db * N_DIM;
    float v = 1e30f;
    #pragma unroll
    for (int s = 0; s < SPLIT; ++s)
        v = fminf(v, ws[((size_t)db * SPLIT + s) * N_DIM + n]);
    for (int off = 32; off > 0; off >>= 1)
        v += __shfl_down(v, off, 64);
    __shared__ float wsum[4];
    const int lane = threadIdx.x & 63, w = threadIdx.x >> 6;
    if (lane == 0) wsum[w] = v;
    __syncthreads();
    if (threadIdx.x == 0) {
        const float t = wsum[0] + wsum[1] + wsum[2] + wsum[3];
        atomicAdd(out, t * scale);
    }
}

extern "C" void kernel_launch(void* const* d_in, const int* in_sizes, int n_in,
                              void* d_out, int out_size, void* d_ws, size_t ws_size,
                              hipStream_t stream) {
    const float* pred = (const float*)d_in[0];
    const float* gt   = (const float*)d_in[1];
    float* out = (float*)d_out;
    float* ws  = (float*)d_ws;     // needs 2*B*SPLIT*N*4 = 4 MiB

    hipMemsetAsync(out, 0, sizeof(float), stream);

    dim3 grid(N_DIM / (BLOCK * PPT), SPLIT, 2 * B_DIM);  // 8 x 8 x 16 = 1024 blocks
    chamfer_partial<<<grid, BLOCK, 0, stream>>>(pred, gt, ws);

    chamfer_reduce<<<(2 * B_DIM * N_DIM) / 256, 256, 0, stream>>>(ws, out);
}

// Round 3
// 141.478 us; speedup vs baseline: 1.2161x; 1.0377x over previous
//
#include <hip/hip_runtime.h>

// Chamfer distance: B=8, N=M=8192, D=3, fp32.
// R3: (a) SPLIT=16/TILE=512 -> 2048 blocks = 8 waves/SIMD (R2 was 4, Occ 30%).
//     (b) cross-split min via device atomicMin on order-preserving u32 keys:
//         ws = 512 KB, single-pass reduce, no split loop (R2 spent ~50us there).
// Inner pair = 3 FMA + 1 MIN (tile holds (-2gx,-2gy,-2gz,|g|^2)).
// VALU floor: 1.074G pairs * 4 / 64 lanes / 1024 SIMDs * 2cyc @2.4GHz = 55us.

#define B_DIM 8
#define N_DIM 8192
#define TILE  512
#define SPLIT 16
#define PPT   4
#define BLOCK 256

__device__ __forceinline__ unsigned int f32_to_ordered_u32(float f) {
    unsigned int u = __float_as_uint(f);
    return (u & 0x80000000u) ? ~u : (u | 0x80000000u);
}
__device__ __forceinline__ float ordered_u32_to_f32(unsigned int k) {
    return __uint_as_float((k & 0x80000000u) ? (k & 0x7fffffffu) : ~k);
}

__global__ __launch_bounds__(BLOCK, 8) void chamfer_partial(
    const float* __restrict__ pred, const float* __restrict__ gt,
    unsigned int* __restrict__ ws)
{
    __shared__ float4 tile[TILE];   // 8 KB
    const int tid   = threadIdx.x;
    const int z     = blockIdx.z;        // 0..15 : b + dir*8
    const int b     = z & (B_DIM - 1);
    const int dir   = z >> 3;            // 0: pred->gt, 1: gt->pred
    const int s     = blockIdx.y;        // M-split
    const int chunk = blockIdx.x;        // N-chunk

    const float* src  = dir ? gt   : pred;
    const float* dst  = dir ? pred : gt;
    const float* srcb = src + (size_t)b * N_DIM * 3;
    const float* dstb = dst + (size_t)b * N_DIM * 3;

    // stage this split's dst points: (-2gx,-2gy,-2gz,|g|^2)
    #pragma unroll
    for (int k = 0; k < TILE / BLOCK; ++k) {
        const int idx = k * BLOCK + tid;
        const int m = s * TILE + idx;
        const float gx = dstb[m*3+0], gy = dstb[m*3+1], gz = dstb[m*3+2];
        const float gn = gx*gx + gy*gy + gz*gz;
        tile[idx] = make_float4(-2.0f*gx, -2.0f*gy, -2.0f*gz, gn);
    }

    // 4 source points per thread
    float px[PPT], py[PPT], pz[PPT], pn[PPT], best[PPT];
    const int nbase = chunk * (BLOCK * PPT) + tid;
    #pragma unroll
    for (int p = 0; p < PPT; ++p) {
        const int n = nbase + p * BLOCK;
        px[p] = srcb[n*3+0]; py[p] = srcb[n*3+1]; pz[p] = srcb[n*3+2];
        pn[p] = px[p]*px[p] + py[p]*py[p] + pz[p]*pz[p];
        best[p] = 1e30f;
    }

    __syncthreads();
    #pragma unroll 8
    for (int j = 0; j < TILE; ++j) {
        const float4 g = tile[j];    // wave-uniform -> LDS broadcast
        #pragma unroll
        for (int p = 0; p < PPT; ++p) {
            const float d = fmaf(g.x, px[p], fmaf(g.y, py[p],
                             fmaf(g.z, pz[p], g.w)));
            best[p] = fminf(best[p], d);
        }
    }

    // ws layout: [dir][b][n] as order-preserving u32; init 0xFF by memset
    unsigned int* wsb = ws + ((size_t)dir * B_DIM + b) * N_DIM;
    #pragma unroll
    for (int p = 0; p < PPT; ++p)
        atomicMin(&wsb[nbase + p * BLOCK], f32_to_ordered_u32(best[p] + pn[p]));
}

__global__ __launch_bounds__(256) void chamfer_reduce(
    const unsigned int* __restrict__ ws, float* __restrict__ out)
{
    const float scale = 100.0f * 0.5f / ((float)B_DIM * (float)N_DIM);
    const int i = (blockIdx.x * 256 + threadIdx.x) * 4;   // over 2*B*N
    const uint4 k = *(const uint4*)(ws + i);
    float v = ordered_u32_to_f32(k.x) + ordered_u32_to_f32(k.y)
            + ordered_u32_to_f32(k.z) + ordered_u32_to_f32(k.w);
    for (int off = 32; off > 0; off >>= 1)
        v += __shfl_down(v, off, 64);
    __shared__ float wsum[4];
    const int lane = threadIdx.x & 63, w = threadIdx.x >> 6;
    if (lane == 0) wsum[w] = v;
    __syncthreads();
    if (threadIdx.x == 0) {
        const float t = wsum[0] + wsum[1] + wsum[2] + wsum[3];
        atomicAdd(out, t * scale);
    }
}

extern "C" void kernel_launch(void* const* d_in, const int* in_sizes, int n_in,
                              void* d_out, int out_size, void* d_ws, size_t ws_size,
                              hipStream_t stream) {
    const float* pred = (const float*)d_in[0];
    const float* gt   = (const float*)d_in[1];
    float* out = (float*)d_out;
    unsigned int* ws = (unsigned int*)d_ws;   // 2*B*N*4 = 512 KB

    hipMemsetAsync(out, 0, sizeof(float), stream);
    hipMemsetAsync(ws, 0xFF, (size_t)2 * B_DIM * N_DIM * sizeof(unsigned int), stream);

    dim3 grid(N_DIM / (BLOCK * PPT), SPLIT, 2 * B_DIM);  // 8 x 16 x 16 = 2048 blocks
    chamfer_partial<<<grid, BLOCK, 0, stream>>>(pred, gt, ws);

    chamfer_reduce<<<(2 * B_DIM * N_DIM) / (256 * 4), 256, 0, stream>>>(ws, out);
}